// Round 1
// baseline (327.189 us; speedup 1.0000x reference)
//
#include <hip/hip_runtime.h>
#include <math.h>

#define BB 8
#define MI 16
#define HH 640
#define WW 640
#define NN (HH*WW)          // 409600 pixels per image
#define CEPS 1e-12f
#define GPB 128             // blocks per batch for the big passes
#define PPB (NN / GPB)      // 3200 pixels per block
#define TPB 256

// ws float layout:
//   [0,640)      sum_k[b][m][5]   (4 channel sums + count)
//   [640,1152)   G[b][m][4]
//   [1152,1280)  valid[b][m]
//   [1280,1536)  st[b][m][2]      (pull loss sum, text pixel count)
#define WS_SUMK 0
#define WS_G    640
#define WS_VAL  1152
#define WS_ST   1280
#define WS_FLOATS 1536

__global__ __launch_bounds__(TPB) void k_kernel_sums(
    const float* __restrict__ outputs, const int* __restrict__ gt_kernels,
    float* __restrict__ ws) {
  __shared__ float s[MI * 5];
  const int b = blockIdx.y;
  for (int i = threadIdx.x; i < MI * 5; i += TPB) s[i] = 0.f;
  __syncthreads();
  const float* sim0 = outputs + (size_t)(b * 8 + 4) * NN;
  const int* gk = gt_kernels + (size_t)b * NN;
  const int start = blockIdx.x * PPB;
  for (int n = start + threadIdx.x; n < start + PPB; n += TPB) {
    const int id = gk[n];
    const float x0 = sim0[n];
    const float x1 = sim0[n + NN];
    const float x2 = sim0[n + 2 * NN];
    const float x3 = sim0[n + 3 * NN];
    atomicAdd(&s[id * 5 + 0], x0);
    atomicAdd(&s[id * 5 + 1], x1);
    atomicAdd(&s[id * 5 + 2], x2);
    atomicAdd(&s[id * 5 + 3], x3);
    atomicAdd(&s[id * 5 + 4], 1.f);
  }
  __syncthreads();
  for (int i = threadIdx.x; i < MI * 5; i += TPB)
    atomicAdd(&ws[WS_SUMK + b * MI * 5 + i], s[i]);
}

__global__ void k_finalize_G(float* __restrict__ ws) {
  const int j = threadIdx.x;            // j = b*MI + m, 128 threads
  if (j >= BB * MI) return;
  const int m = j & (MI - 1);
  const float cnt = ws[WS_SUMK + j * 5 + 4];
  const float inv = 1.f / fmaxf(cnt, 1.f);
  ws[WS_G + j * 4 + 0] = ws[WS_SUMK + j * 5 + 0] * inv;
  ws[WS_G + j * 4 + 1] = ws[WS_SUMK + j * 5 + 1] * inv;
  ws[WS_G + j * 4 + 2] = ws[WS_SUMK + j * 5 + 2] * inv;
  ws[WS_G + j * 4 + 3] = ws[WS_SUMK + j * 5 + 3] * inv;
  ws[WS_VAL + j] = (cnt > 0.f && m >= 1) ? 1.f : 0.f;
}

__global__ __launch_bounds__(TPB) void k_pull(
    const float* __restrict__ outputs, const int* __restrict__ gt_texts,
    float* __restrict__ ws) {
  __shared__ float sG[MI * 5];   // stride 5 to spread banks; slots 0..3 used
  __shared__ float st[MI * 2];   // (sum, cnt) per instance
  const int b = blockIdx.y;
  for (int i = threadIdx.x; i < MI * 4; i += TPB) {
    const int m = i >> 2, c = i & 3;
    sG[m * 5 + c] = ws[WS_G + (b * MI + m) * 4 + c];
  }
  for (int i = threadIdx.x; i < MI * 2; i += TPB) st[i] = 0.f;
  __syncthreads();
  const float* sim0 = outputs + (size_t)(b * 8 + 4) * NN;
  const int* tt = gt_texts + (size_t)b * NN;
  const int start = blockIdx.x * PPB;
  for (int n = start + threadIdx.x; n < start + PPB; n += TPB) {
    const int id = tt[n];
    const float d0 = sim0[n]          - sG[id * 5 + 0];
    const float d1 = sim0[n + NN]     - sG[id * 5 + 1];
    const float d2 = sim0[n + 2 * NN] - sG[id * 5 + 2];
    const float d3 = sim0[n + 3 * NN] - sG[id * 5 + 3];
    const float dist = sqrtf(d0 * d0 + d1 * d1 + d2 * d2 + d3 * d3 + CEPS) - 0.5f;
    const float dm = fmaxf(dist, 0.f);
    const float l = log1pf(dm * dm);
    atomicAdd(&st[id * 2 + 0], l);
    atomicAdd(&st[id * 2 + 1], 1.f);
  }
  __syncthreads();
  for (int i = threadIdx.x; i < MI * 2; i += TPB)
    atomicAdd(&ws[WS_ST + b * MI * 2 + i], st[i]);
}

__global__ void k_final(const float* __restrict__ ws, float* __restrict__ out) {
  const int b = threadIdx.x;
  if (b >= BB) return;
  const float* G = ws + WS_G;
  const float* valid = ws + WS_VAL;
  const float* st = ws + WS_ST;
  float nv = 0.f;
  for (int m = 0; m < MI; m++) nv += valid[b * MI + m];
  float pull = 0.f;
  for (int m = 0; m < MI; m++) {
    const int j = b * MI + m;
    const float per = st[j * 2 + 0] / fmaxf(st[j * 2 + 1], 1.f);
    pull += per * valid[j];
  }
  pull /= fmaxf(nv, 1.f);
  float push = 0.f;
  for (int i = 0; i < MI; i++) {
    if (valid[b * MI + i] == 0.f) continue;
    for (int j = i + 1; j < MI; j++) {
      if (valid[b * MI + j] == 0.f) continue;
      float d2 = CEPS;
      for (int c = 0; c < 4; c++) {
        const float df = G[(b * MI + i) * 4 + c] - G[(b * MI + j) * 4 + c];
        d2 += df * df;
      }
      const float dk = sqrtf(d2);
      const float t = fmaxf(3.f - dk, 0.f);
      push += log1pf(t * t);
    }
  }
  const float denom = nv * (nv - 1.f);
  push = (nv > 1.f) ? push / fmaxf(denom, 1.f) : 0.f;
  out[b] = pull;
  out[BB + b] = push;
}

extern "C" void kernel_launch(void* const* d_in, const int* in_sizes, int n_in,
                              void* d_out, int out_size, void* d_ws, size_t ws_size,
                              hipStream_t stream) {
  const float* outputs = (const float*)d_in[0];
  const int* gt_texts = (const int*)d_in[1];
  const int* gt_kernels = (const int*)d_in[2];
  float* ws = (float*)d_ws;
  float* out = (float*)d_out;

  hipMemsetAsync(d_ws, 0, WS_FLOATS * sizeof(float), stream);

  dim3 grid(GPB, BB);
  k_kernel_sums<<<grid, TPB, 0, stream>>>(outputs, gt_kernels, ws);
  k_finalize_G<<<1, 128, 0, stream>>>(ws);
  k_pull<<<grid, TPB, 0, stream>>>(outputs, gt_texts, ws);
  k_final<<<1, 64, 0, stream>>>(ws, out);
}

// Round 2
// 254.195 us; speedup vs baseline: 1.2872x; 1.2872x over previous
//
#include <hip/hip_runtime.h>
#include <math.h>

#define BB 8
#define MI 16
#define NN 409600          // 640*640
#define CEPS 1e-12f
#define GPB 64             // blocks per batch image
#define TPB 256
#define CHUNKS 400         // NN / 1024 pixels-per-chunk (256 thr * 4 px)

// ws float layout:
//   [0,512)     sum[b][c][m] = ws[b*64 + c*16 + m]   (kernel channel sums)
//   [512,640)   cntk[b][m]   (int)
//   [640,768)   st[b][m]     (pull loss sums)
//   [768,896)   cntt[b][m]   (int)
//   [896,1408)  G[b][m][4]   (float4-aligned: 896*4 = 3584 B)
//   [1408,1536) valid[b][m]
#define WS_SUM  0
#define WS_CNTK 512
#define WS_ST   640
#define WS_CNTT 768
#define WS_G    896
#define WS_VAL  1408
#define WS_ZERO_FLOATS 896   // regions accumulated via atomics must start at 0

// pick value v (= c*16+m) from the four unrolled register arrays; v is a
// compile-time constant after full unroll so this folds to a register ref
#define VALK(v) ((v) < 16 ? a0[(v) & 15] : (v) < 32 ? a1[(v) & 15] \
               : (v) < 48 ? a2[(v) & 15] : a3[(v) & 15])

__global__ __launch_bounds__(TPB) void k_sums(
    const float* __restrict__ outputs, const int* __restrict__ gt_kernels,
    float* __restrict__ ws) {
  __shared__ float red[TPB * 36];      // 36.9 KB, pad 36 (32+4) floats/row
  __shared__ unsigned int scnt[MI];
  const int b = blockIdx.y;
  const int tid = threadIdx.x;
  if (tid < MI) scnt[tid] = 0u;
  __syncthreads();

  float a0[MI], a1[MI], a2[MI], a3[MI];
  unsigned int wcnt[MI];
#pragma unroll
  for (int m = 0; m < MI; m++) { a0[m] = 0.f; a1[m] = 0.f; a2[m] = 0.f; a3[m] = 0.f; wcnt[m] = 0u; }

  const float* s0 = outputs + (size_t)(b * 8 + 4) * NN;
  const int* gkb = gt_kernels + (size_t)b * NN;

  for (int c = blockIdx.x; c < CHUNKS; c += GPB) {
    const int pix = c * 1024 + tid * 4;
    const int4 id4 = *(const int4*)(gkb + pix);
    const float4 x0 = *(const float4*)(s0 + pix);
    const float4 x1 = *(const float4*)(s0 + NN + pix);
    const float4 x2 = *(const float4*)(s0 + 2 * NN + pix);
    const float4 x3 = *(const float4*)(s0 + 3 * NN + pix);
#define SLOTK(IDC, XC)                                                       \
    {                                                                        \
      const int id = id4.IDC;                                                \
      _Pragma("unroll")                                                      \
      for (int m = 0; m < MI; m++) {                                         \
        const bool e = (id == m);                                            \
        wcnt[m] += (unsigned)__popcll(__ballot(e));                          \
        const float f = e ? 1.f : 0.f;                                       \
        a0[m] += f * x0.XC; a1[m] += f * x1.XC;                              \
        a2[m] += f * x2.XC; a3[m] += f * x3.XC;                              \
      }                                                                      \
    }
    SLOTK(x, x) SLOTK(y, y) SLOTK(z, z) SLOTK(w, w)
#undef SLOTK
  }

  // wave-uniform counts: lane 0 of each wave flushes to LDS, then global
  if ((tid & 63) == 0) {
#pragma unroll
    for (int m = 0; m < MI; m++) atomicAdd(&scnt[m], wcnt[m]);
  }

  // block-reduce the 64 float sums in 2 rounds of 32 values
#pragma unroll
  for (int r = 0; r < 2; r++) {
    __syncthreads();
#pragma unroll
    for (int j = 0; j < 32; j++) red[tid * 36 + j] = VALK(r * 32 + j);
    __syncthreads();
    const int m = tid & 31, grp = tid >> 5;   // 8 groups of 32 rows
    float p = 0.f;
#pragma unroll
    for (int k = 0; k < 32; k++) p += red[(grp * 32 + k) * 36 + m];
    __syncthreads();
    red[grp * 36 + m] = p;
    __syncthreads();
    if (tid < 32) {
      float t = 0.f;
#pragma unroll
      for (int g = 0; g < 8; g++) t += red[g * 36 + tid];
      atomicAdd(&ws[WS_SUM + b * 64 + r * 32 + tid], t);
    }
  }
  __syncthreads();
  if (tid < MI) atomicAdd(&((int*)ws)[WS_CNTK + b * MI + tid], (int)scnt[tid]);
}

__global__ void k_finalize_G(float* __restrict__ ws) {
  const int j = threadIdx.x;               // j = b*MI + m
  if (j >= BB * MI) return;
  const int b = j >> 4, m = j & 15;
  const int cnt = ((const int*)ws)[WS_CNTK + j];
  const float inv = 1.f / fmaxf((float)cnt, 1.f);
  ws[WS_G + j * 4 + 0] = ws[WS_SUM + b * 64 + 0 * 16 + m] * inv;
  ws[WS_G + j * 4 + 1] = ws[WS_SUM + b * 64 + 1 * 16 + m] * inv;
  ws[WS_G + j * 4 + 2] = ws[WS_SUM + b * 64 + 2 * 16 + m] * inv;
  ws[WS_G + j * 4 + 3] = ws[WS_SUM + b * 64 + 3 * 16 + m] * inv;
  ws[WS_VAL + j] = (cnt > 0 && m >= 1) ? 1.f : 0.f;
}

__global__ __launch_bounds__(TPB) void k_pull(
    const float* __restrict__ outputs, const int* __restrict__ gt_texts,
    float* __restrict__ ws) {
  __shared__ float red[TPB * 20];      // 20 KB, pad 20 (16+4)
  __shared__ unsigned int scnt[MI];
  __shared__ float4 sG[MI];
  const int b = blockIdx.y;
  const int tid = threadIdx.x;
  if (tid < MI) {
    scnt[tid] = 0u;
    sG[tid] = ((const float4*)(ws + WS_G))[b * MI + tid];
  }
  __syncthreads();

  float al[MI];
  unsigned int wcnt[MI];
#pragma unroll
  for (int m = 0; m < MI; m++) { al[m] = 0.f; wcnt[m] = 0u; }

  const float* s0 = outputs + (size_t)(b * 8 + 4) * NN;
  const int* ttb = gt_texts + (size_t)b * NN;

  for (int c = blockIdx.x; c < CHUNKS; c += GPB) {
    const int pix = c * 1024 + tid * 4;
    const int4 id4 = *(const int4*)(ttb + pix);
    const float4 x0 = *(const float4*)(s0 + pix);
    const float4 x1 = *(const float4*)(s0 + NN + pix);
    const float4 x2 = *(const float4*)(s0 + 2 * NN + pix);
    const float4 x3 = *(const float4*)(s0 + 3 * NN + pix);
#define SLOTP(IDC, XC)                                                       \
    {                                                                        \
      const int id = id4.IDC;                                                \
      const float4 g = sG[id];                                               \
      const float d0 = x0.XC - g.x, d1 = x1.XC - g.y;                        \
      const float d2 = x2.XC - g.z, d3 = x3.XC - g.w;                        \
      const float dist = sqrtf(d0*d0 + d1*d1 + d2*d2 + d3*d3 + CEPS) - 0.5f; \
      const float dm = fmaxf(dist, 0.f);                                     \
      const float l = log1pf(dm * dm);                                       \
      _Pragma("unroll")                                                      \
      for (int m = 0; m < MI; m++) {                                         \
        const bool e = (id == m);                                            \
        wcnt[m] += (unsigned)__popcll(__ballot(e));                          \
        al[m] += (e ? 1.f : 0.f) * l;                                        \
      }                                                                      \
    }
    SLOTP(x, x) SLOTP(y, y) SLOTP(z, z) SLOTP(w, w)
#undef SLOTP
  }

  if ((tid & 63) == 0) {
#pragma unroll
    for (int m = 0; m < MI; m++) atomicAdd(&scnt[m], wcnt[m]);
  }

  // block-reduce the 16 loss sums in one round
  __syncthreads();
#pragma unroll
  for (int j = 0; j < MI; j++) red[tid * 20 + j] = al[j];
  __syncthreads();
  const int m = tid & 15, grp = tid >> 4;   // 16 groups of 16 rows
  float p = 0.f;
#pragma unroll
  for (int k = 0; k < 16; k++) p += red[(grp * 16 + k) * 20 + m];
  __syncthreads();
  red[grp * 20 + m] = p;
  __syncthreads();
  if (tid < MI) {
    float t = 0.f;
#pragma unroll
    for (int g = 0; g < 16; g++) t += red[g * 20 + tid];
    atomicAdd(&ws[WS_ST + b * MI + tid], t);
    atomicAdd(&((int*)ws)[WS_CNTT + b * MI + tid], (int)scnt[tid]);
  }
}

__global__ void k_final(const float* __restrict__ ws, float* __restrict__ out) {
  const int b = threadIdx.x;
  if (b >= BB) return;
  const float* G = ws + WS_G;
  const float* valid = ws + WS_VAL;
  float nv = 0.f;
  for (int m = 0; m < MI; m++) nv += valid[b * MI + m];
  float pull = 0.f;
  for (int m = 0; m < MI; m++) {
    const int j = b * MI + m;
    const float cnt = (float)((const int*)ws)[WS_CNTT + j];
    const float per = ws[WS_ST + j] / fmaxf(cnt, 1.f);
    pull += per * valid[j];
  }
  pull /= fmaxf(nv, 1.f);
  float push = 0.f;
  for (int i = 0; i < MI; i++) {
    if (valid[b * MI + i] == 0.f) continue;
    for (int j = i + 1; j < MI; j++) {
      if (valid[b * MI + j] == 0.f) continue;
      float d2 = CEPS;
      for (int c = 0; c < 4; c++) {
        const float df = G[(b * MI + i) * 4 + c] - G[(b * MI + j) * 4 + c];
        d2 += df * df;
      }
      const float dk = sqrtf(d2);
      const float t = fmaxf(3.f - dk, 0.f);
      push += log1pf(t * t);
    }
  }
  const float denom = nv * (nv - 1.f);
  push = (nv > 1.f) ? push / fmaxf(denom, 1.f) : 0.f;
  out[b] = pull;
  out[BB + b] = push;
}

extern "C" void kernel_launch(void* const* d_in, const int* in_sizes, int n_in,
                              void* d_out, int out_size, void* d_ws, size_t ws_size,
                              hipStream_t stream) {
  const float* outputs = (const float*)d_in[0];
  const int* gt_texts = (const int*)d_in[1];
  const int* gt_kernels = (const int*)d_in[2];
  float* ws = (float*)d_ws;
  float* out = (float*)d_out;

  hipMemsetAsync(d_ws, 0, WS_ZERO_FLOATS * sizeof(float), stream);

  dim3 grid(GPB, BB);
  k_sums<<<grid, TPB, 0, stream>>>(outputs, gt_kernels, ws);
  k_finalize_G<<<1, 128, 0, stream>>>(ws);
  k_pull<<<grid, TPB, 0, stream>>>(outputs, gt_texts, ws);
  k_final<<<1, 64, 0, stream>>>(ws, out);
}